// Round 1
// baseline (482.713 us; speedup 1.0000x reference)
//
#include <hip/hip_runtime.h>
#include <hip/hip_bf16.h>

// Problem dims (fixed by reference):
//   X  = spike_input [N=64, I=256, T=500] fp32
//   W1 = [H=1024, I=256] fp32
//   W2 = [O=18, H=1024] fp32
//   out s2 [N=64, O=18, T=500] fp32
// ws layout:
//   [0, 131072000)          y1 / s1 in-place, fp32 [N][T][H]
//   [131072000, 133376000)  y2, fp32 [N][T][O]

#define NN 64
#define II 256
#define HH 1024
#define OO 18
#define TT 500

// fp32-exact recurrence constants (double literals rounded once to fp32,
// matching jnp.float32(math.exp(...)))
#define D_SR 0.9048374180359595f   // exp(-1/10)
#define C_SR 0.27182818284590454f  // e/10
#define D_RF 0.36787944117144233f  // exp(-1)
#define C_RF 2.718281828459045f    // e
#define THETA 10.0f
#define REFS (-20.0f)              // -scaleRef*theta

// ---------------- K1: GEMM1  y1[n][t][h] = sum_i X[n][i][t] * W1[h][i] -----
#define BT 64
#define BH 64
#define BK 16

__launch_bounds__(256)
__global__ void gemm1_kernel(const float* __restrict__ X,
                             const float* __restrict__ W1,
                             float* __restrict__ Y) {
    const int n  = blockIdx.z;
    const int t0 = blockIdx.x * BT;
    const int h0 = blockIdx.y * BH;
    const int tid = threadIdx.x;

    __shared__ __align__(16) float As[BK][BT + 4];
    __shared__ __align__(16) float Ws[BK][BH + 4];

    const float* Xn = X + (size_t)n * II * TT;
    float acc[4][4] = {};

    const int col = (tid & 15) * 4;  // h within tile
    const int row = (tid >> 4) * 4;  // t within tile

    for (int i0 = 0; i0 < II; i0 += BK) {
        // stage A^T tile: As[i][t] <- X[n][i0+i][t0+t], coalesced along t
        {
            int e  = tid * 4;
            int ii = e >> 6;
            int tt = e & 63;
            int gt = t0 + tt;
            const float* src = Xn + (size_t)(i0 + ii) * TT + gt;
            if (t0 + BT <= TT) {
                float4 v = *(const float4*)src;
                As[ii][tt + 0] = v.x; As[ii][tt + 1] = v.y;
                As[ii][tt + 2] = v.z; As[ii][tt + 3] = v.w;
            } else {
#pragma unroll
                for (int j = 0; j < 4; j++)
                    As[ii][tt + j] = (gt + j < TT) ? src[j] : 0.0f;
            }
        }
        // stage W tile transposed: Ws[i][h] <- W1[h0+h][i0+i]
        {
            int hh = tid >> 2;
            int iq = (tid & 3) * 4;
            float4 w = *(const float4*)(W1 + (size_t)(h0 + hh) * II + i0 + iq);
            Ws[iq + 0][hh] = w.x; Ws[iq + 1][hh] = w.y;
            Ws[iq + 2][hh] = w.z; Ws[iq + 3][hh] = w.w;
        }
        __syncthreads();

#pragma unroll
        for (int k = 0; k < BK; k++) {
            float4 av = *(const float4*)&As[k][row];
            float4 wv = *(const float4*)&Ws[k][col];
            float ar[4] = {av.x, av.y, av.z, av.w};
            float wc[4] = {wv.x, wv.y, wv.z, wv.w};
#pragma unroll
            for (int r = 0; r < 4; r++)
#pragma unroll
                for (int c = 0; c < 4; c++)
                    acc[r][c] += ar[r] * wc[c];
        }
        __syncthreads();
    }

    // epilogue: Y[n][t][h]
    float* Yn = Y + (size_t)n * TT * HH;
#pragma unroll
    for (int r = 0; r < 4; r++) {
        int gt = t0 + row + r;
        if (gt < TT) {
            float4 v = make_float4(acc[r][0], acc[r][1], acc[r][2], acc[r][3]);
            *(float4*)(Yn + (size_t)gt * HH + h0 + col) = v;
        }
    }
}

// ---------------- K2: scan1 (psp + spike_layer), in place y1 -> s1 ---------
__launch_bounds__(256)
__global__ void scan1_kernel(float* __restrict__ Y) {
    const int n = blockIdx.y;
    const int h = blockIdx.x * 256 + threadIdx.x;
    float* p = Y + (size_t)n * TT * HH + h;

    float p1 = 0.f, a1 = 0.f, p2 = 0.f, a2 = 0.f;
    float buf[4];
#pragma unroll
    for (int j = 0; j < 4; j++) buf[j] = p[(size_t)j * HH];

    for (int t = 0; t < TT; t++) {
        float x  = buf[t & 3];
        float xn = (t + 4 < TT) ? p[(size_t)(t + 4) * HH] : 0.0f;
        // psp
        a1 = D_SR * (a1 + p1);
        p1 = D_SR * p1 + x;
        float ut = C_SR * a1;
        // spike layer
        a2 = D_RF * (a2 + p2);
        float u = ut + C_RF * a2;
        float s = (u >= THETA) ? 1.0f : 0.0f;
        p2 = D_RF * p2 + REFS * s;
        p[(size_t)t * HH] = s;
        buf[t & 3] = xn;
    }
}

// ---------------- K3: GEMM2  y2[n][t][o] = sum_h s1[n][t][h] * W2[o][h] ----
__launch_bounds__(256)
__global__ void gemm2_kernel(const float* __restrict__ S1,
                             const float* __restrict__ W2,
                             float* __restrict__ Y2) {
    const int lane = threadIdx.x & 63;
    const int wave = threadIdx.x >> 6;
    const int task = blockIdx.x * 4 + wave;  // 0 .. N*T-1
    const int n = task / TT;
    const int t = task % TT;

    const float* s = S1 + (size_t)n * TT * HH + (size_t)t * HH + lane;
    float sv[16];
#pragma unroll
    for (int k = 0; k < 16; k++) sv[k] = s[k * 64];

    float* y2 = Y2 + (size_t)n * TT * OO + (size_t)t * OO;
    for (int o = 0; o < OO; o++) {
        const float* w = W2 + (size_t)o * HH + lane;
        float acc = 0.f;
#pragma unroll
        for (int k = 0; k < 16; k++) acc += sv[k] * w[k * 64];
        acc += __shfl_down(acc, 32);
        acc += __shfl_down(acc, 16);
        acc += __shfl_down(acc, 8);
        acc += __shfl_down(acc, 4);
        acc += __shfl_down(acc, 2);
        acc += __shfl_down(acc, 1);
        if (lane == 0) y2[o] = acc;
    }
}

// ---------------- K4: scan2, y2 -> out [N][O][T] ---------------------------
#define CT 125  // 500/4 chunk
__launch_bounds__(64)
__global__ void scan2_kernel(const float* __restrict__ Y2,
                             float* __restrict__ Out) {
    const int n = blockIdx.x;
    const int tid = threadIdx.x;
    __shared__ float ybuf[CT * OO];
    __shared__ float sbuf[CT * OO];

    float p1 = 0.f, a1 = 0.f, p2 = 0.f, a2 = 0.f;
    const float* yn = Y2 + (size_t)n * TT * OO;
    float* on = Out + (size_t)n * OO * TT;

    for (int c = 0; c < 4; c++) {
        for (int e = tid; e < CT * OO; e += 64) ybuf[e] = yn[c * CT * OO + e];
        __syncthreads();
        if (tid < OO) {
            const int o = tid;
            for (int tt = 0; tt < CT; tt++) {
                float x = ybuf[tt * OO + o];
                a1 = D_SR * (a1 + p1);
                p1 = D_SR * p1 + x;
                float ut = C_SR * a1;
                a2 = D_RF * (a2 + p2);
                float u = ut + C_RF * a2;
                float s = (u >= THETA) ? 1.0f : 0.0f;
                p2 = D_RF * p2 + REFS * s;
                sbuf[tt * OO + o] = s;
            }
        }
        __syncthreads();
        for (int e = tid; e < CT * OO; e += 64) {
            int o  = e / CT;
            int tt = e % CT;
            on[(size_t)o * TT + c * CT + tt] = sbuf[tt * OO + o];
        }
        __syncthreads();
    }
}

extern "C" void kernel_launch(void* const* d_in, const int* in_sizes, int n_in,
                              void* d_out, int out_size, void* d_ws, size_t ws_size,
                              hipStream_t stream) {
    const float* X  = (const float*)d_in[0];
    const float* W1 = (const float*)d_in[1];
    const float* W2 = (const float*)d_in[2];
    float* out = (float*)d_out;

    float* y1 = (float*)d_ws;                                  // 131,072,000 B
    float* y2 = (float*)((char*)d_ws + (size_t)NN * TT * HH * 4);  // 2,304,000 B

    // K1: y1 = X^T * W1^T per n
    {
        dim3 grid((TT + BT - 1) / BT, HH / BH, NN);  // 8 x 16 x 64
        gemm1_kernel<<<grid, 256, 0, stream>>>(X, W1, y1);
    }
    // K2: scan1 in place (y1 -> s1)
    {
        dim3 grid(HH / 256, NN);  // 4 x 64
        scan1_kernel<<<grid, 256, 0, stream>>>(y1);
    }
    // K3: y2 = s1 * W2^T
    {
        dim3 grid(NN * TT / 4);  // 8000 blocks, 4 waves each, 1 (n,t) per wave
        gemm2_kernel<<<grid, 256, 0, stream>>>(y1, W2, y2);
    }
    // K4: scan2 -> out
    {
        scan2_kernel<<<dim3(NN), 64, 0, stream>>>(y2, out);
    }
}

// Round 2
// 389.420 us; speedup vs baseline: 1.2396x; 1.2396x over previous
//
#include <hip/hip_runtime.h>
#include <hip/hip_bf16.h>

// SNN forward: GEMM1(X*W1^T) -> psp+spike scan -> GEMM2(s1*W2^T) -> scan -> out
// f16 split-2 trick: W = hi + lo (both f16), residual ~2^-24 relative => MFMA
// f32-accumulate gives fp32-grade results. X and spikes are exact in f16.

#define NN 64
#define II 256
#define HH 1024
#define OO 18
#define TT 500

#define D_SR 0.9048374180359595f   // exp(-1/10)
#define C_SR 0.27182818284590454f  // e/10
#define D_RF 0.36787944117144233f  // exp(-1)
#define C_RF 2.718281828459045f    // e
#define THETA 10.0f
#define REFS (-20.0f)

typedef _Float16 f16;
typedef _Float16 f16x8 __attribute__((ext_vector_type(8)));
typedef float f32x4 __attribute__((ext_vector_type(4)));

__device__ __forceinline__ void gl2lds16(const void* g, void* l) {
    __builtin_amdgcn_global_load_lds(
        (const __attribute__((address_space(1))) void*)g,
        (__attribute__((address_space(3))) void*)l, 16, 0, 0);
}

// ---------------- prep: X [N][I][T] f32 -> Xb [N*T][I] f16 (transpose) -----
__launch_bounds__(256)
__global__ void prep_x(const float* __restrict__ X, f16* __restrict__ Xb) {
    __shared__ float tile[64][65];
    const int n = blockIdx.z, i0 = blockIdx.y * 64, t0 = blockIdx.x * 64;
    const int tx = threadIdx.x & 63, q = threadIdx.x >> 6;
    const float* Xn = X + (size_t)n * II * TT;
#pragma unroll 4
    for (int j = 0; j < 16; ++j) {
        int il = j * 4 + q;
        int t = t0 + tx;
        tile[il][tx] = (t < TT) ? Xn[(size_t)(i0 + il) * TT + t] : 0.f;
    }
    __syncthreads();
#pragma unroll 4
    for (int j = 0; j < 16; ++j) {
        int tl = j * 4 + q;
        int t = t0 + tl;
        if (t < TT)
            Xb[((size_t)n * TT + t) * II + i0 + tx] = (f16)tile[tx][tl];
    }
}

// ---------------- prep: W1 -> f16 hi/lo [H][I] ------------------------------
__launch_bounds__(256)
__global__ void prep_w1(const float* __restrict__ W1, f16* __restrict__ Wh,
                        f16* __restrict__ Wl) {
    int idx = blockIdx.x * 256 + threadIdx.x;  // < 1024*256
    float w = W1[idx];
    f16 h = (f16)w;
    f16 l = (f16)(w - (float)h);
    Wh[idx] = h;
    Wl[idx] = l;
}

// ---------------- prep: W2 -> f16 hi/lo [32 padded][H] ----------------------
__launch_bounds__(256)
__global__ void prep_w2(const float* __restrict__ W2, f16* __restrict__ Wh,
                        f16* __restrict__ Wl) {
    int idx = blockIdx.x * 256 + threadIdx.x;  // < 32*1024
    int o = idx >> 10;
    float w = (o < OO) ? W2[idx] : 0.f;
    f16 h = (f16)w;
    f16 l = (f16)(w - (float)h);
    Wh[idx] = h;
    Wl[idx] = l;
}

// ---------------- GEMM1 (MFMA, split-f16): y1_c = Xb_c * W1^T ---------------
// grid: (mtiles, 8); block 256 = 4 waves; 128x128 tile, BK=32, K=256.
__launch_bounds__(256)
__global__ void gemm1_mfma(const f16* __restrict__ Xb, const f16* __restrict__ Wh,
                           const f16* __restrict__ Wl, float* __restrict__ Y,
                           int chunkT, int c) {
    __shared__ __align__(16) f16 As[128 * 32];
    __shared__ __align__(16) f16 Bh[128 * 32];
    __shared__ __align__(16) f16 Bl[128 * 32];

    const int tid = threadIdx.x;
    const int wave = tid >> 6, lane = tid & 63;
    const int m0 = blockIdx.x * 128, h0 = blockIdx.y * 128;
    const int Mrows = NN * chunkT;

    // staging source rows (fixed across K): chunk-local r -> global Xb row
    int ra = m0 + wave * 32 + (lane >> 2);
    int ra2 = ra + 16;
    if (ra > Mrows - 1) ra = Mrows - 1;
    if (ra2 > Mrows - 1) ra2 = Mrows - 1;
    int na = ra / chunkT, na2 = ra2 / chunkT;
    const f16* gA0 = Xb + ((size_t)na * TT + (size_t)c * chunkT + (ra - na * chunkT)) * II + (lane & 3) * 8;
    const f16* gA1 = Xb + ((size_t)na2 * TT + (size_t)c * chunkT + (ra2 - na2 * chunkT)) * II + (lane & 3) * 8;
    const int rb = h0 + wave * 32 + (lane >> 2);
    const f16* gBh0 = Wh + (size_t)rb * II + (lane & 3) * 8;
    const f16* gBl0 = Wl + (size_t)rb * II + (lane & 3) * 8;

    f16* lA0 = As + (wave * 32) * 32;
    f16* lA1 = lA0 + 16 * 32;
    f16* lBh0 = Bh + (wave * 32) * 32;
    f16* lBh1 = lBh0 + 16 * 32;
    f16* lBl0 = Bl + (wave * 32) * 32;
    f16* lBl1 = lBl0 + 16 * 32;

    f32x4 acc[4][4] = {};
    const int wm = wave & 1, wn = wave >> 1;
    const int fr = lane & 15, kq = lane >> 4;

    for (int kk = 0; kk < II / 32; ++kk) {
        const int ko = kk * 32;
        gl2lds16(gA0 + ko, lA0);
        gl2lds16(gA1 + ko, lA1);
        gl2lds16(gBh0 + ko, lBh0);
        gl2lds16(gBh0 + 16 * II + ko, lBh1);
        gl2lds16(gBl0 + ko, lBl0);
        gl2lds16(gBl0 + 16 * II + ko, lBl1);
        __syncthreads();

        f16x8 a[4], bh[4], bl[4];
#pragma unroll
        for (int i = 0; i < 4; ++i) {
            a[i]  = *(const f16x8*)(As + (wm * 64 + i * 16 + fr) * 32 + kq * 8);
            bh[i] = *(const f16x8*)(Bh + (wn * 64 + i * 16 + fr) * 32 + kq * 8);
            bl[i] = *(const f16x8*)(Bl + (wn * 64 + i * 16 + fr) * 32 + kq * 8);
        }
#pragma unroll
        for (int i = 0; i < 4; ++i)
#pragma unroll
            for (int j = 0; j < 4; ++j) {
                acc[i][j] = __builtin_amdgcn_mfma_f32_16x16x32_f16(a[i], bh[j], acc[i][j], 0, 0, 0);
                acc[i][j] = __builtin_amdgcn_mfma_f32_16x16x32_f16(a[i], bl[j], acc[i][j], 0, 0, 0);
            }
        __syncthreads();
    }

    // epilogue: C col = lane&15, row = (lane>>4)*4 + reg (padded rows exist)
#pragma unroll
    for (int i = 0; i < 4; ++i)
#pragma unroll
        for (int j = 0; j < 4; ++j) {
            int rbase = m0 + wm * 64 + i * 16 + kq * 4;
            int cc = h0 + wn * 64 + j * 16 + fr;
            float* p = Y + (size_t)rbase * HH + cc;
#pragma unroll
            for (int r = 0; r < 4; ++r)
                p[(size_t)r * HH] = acc[i][j][r];
        }
}

// ---------------- scan1 (psp + spike), y1_c f32 -> s1b f16, stateful --------
__launch_bounds__(256)
__global__ void scan1_k(const float* __restrict__ Y, f16* __restrict__ S1,
                        float* __restrict__ St, int chunkT, int c) {
    const int h = blockIdx.x * 256 + threadIdx.x;
    const int n = blockIdx.y;
    const int ch = n * HH + h;
    const float* p = Y + (size_t)n * chunkT * HH + h;
    f16* q = S1 + ((size_t)n * TT + (size_t)c * chunkT) * HH + h;

    float p1, a1, p2, a2;
    if (c == 0) {
        p1 = a1 = p2 = a2 = 0.f;
    } else {
        p1 = St[ch]; a1 = St[ch + 65536]; p2 = St[ch + 131072]; a2 = St[ch + 196608];
    }
    float buf[4];
#pragma unroll
    for (int j = 0; j < 4; ++j) buf[j] = p[(size_t)j * HH];

    for (int t = 0; t < chunkT; ++t) {
        float x = buf[t & 3];
        float xn = (t + 4 < chunkT) ? p[(size_t)(t + 4) * HH] : 0.f;
        a1 = D_SR * (a1 + p1);
        p1 = D_SR * p1 + x;
        float ut = C_SR * a1;
        a2 = D_RF * (a2 + p2);
        float u = ut + C_RF * a2;
        float s = (u >= THETA) ? 1.0f : 0.0f;
        p2 = D_RF * p2 + REFS * s;
        q[(size_t)t * HH] = (f16)s;
        buf[t & 3] = xn;
    }
    St[ch] = p1; St[ch + 65536] = a1; St[ch + 131072] = p2; St[ch + 196608] = a2;
}

// ---------------- GEMM2 (MFMA, split-f16): y2 = s1b * W2p^T -----------------
// grid: 250; block 256 = 4 waves; tile 128 rows x 32 o; K=1024, BK=32.
__launch_bounds__(256)
__global__ void gemm2_mfma(const f16* __restrict__ S1, const f16* __restrict__ W2h,
                           const f16* __restrict__ W2l, float* __restrict__ Y2) {
    __shared__ __align__(16) f16 As[128 * 32];
    __shared__ __align__(16) f16 Bh[32 * 32];
    __shared__ __align__(16) f16 Bl[32 * 32];

    const int tid = threadIdx.x;
    const int wave = tid >> 6, lane = tid & 63;
    const int m0 = blockIdx.x * 128;

    const f16* gA0 = S1 + (size_t)(m0 + wave * 32 + (lane >> 2)) * HH + (lane & 3) * 8;
    const f16* gA1 = gA0 + (size_t)16 * HH;
    const f16* gB = (wave < 2 ? W2h : W2l) + (size_t)((wave & 1) * 16 + (lane >> 2)) * HH + (lane & 3) * 8;

    f16* lA0 = As + (wave * 32) * 32;
    f16* lA1 = lA0 + 16 * 32;
    f16* lB = (wave < 2 ? Bh : Bl) + ((wave & 1) * 16) * 32;

    f32x4 acc[2][2] = {};
    const int fr = lane & 15, kq = lane >> 4;

    for (int kk = 0; kk < HH / 32; ++kk) {
        const int ko = kk * 32;
        gl2lds16(gA0 + ko, lA0);
        gl2lds16(gA1 + ko, lA1);
        gl2lds16(gB + ko, lB);
        __syncthreads();

        f16x8 a[2], bh[2], bl[2];
#pragma unroll
        for (int i = 0; i < 2; ++i) {
            a[i]  = *(const f16x8*)(As + (wave * 32 + i * 16 + fr) * 32 + kq * 8);
            bh[i] = *(const f16x8*)(Bh + (i * 16 + fr) * 32 + kq * 8);
            bl[i] = *(const f16x8*)(Bl + (i * 16 + fr) * 32 + kq * 8);
        }
#pragma unroll
        for (int i = 0; i < 2; ++i)
#pragma unroll
            for (int j = 0; j < 2; ++j) {
                acc[i][j] = __builtin_amdgcn_mfma_f32_16x16x32_f16(a[i], bh[j], acc[i][j], 0, 0, 0);
                acc[i][j] = __builtin_amdgcn_mfma_f32_16x16x32_f16(a[i], bl[j], acc[i][j], 0, 0, 0);
            }
        __syncthreads();
    }

#pragma unroll
    for (int i = 0; i < 2; ++i)
#pragma unroll
        for (int j = 0; j < 2; ++j) {
            int rbase = m0 + wave * 32 + i * 16 + kq * 4;
            int cc = j * 16 + fr;
            float* p = Y2 + (size_t)rbase * 32 + cc;
#pragma unroll
            for (int r = 0; r < 4; ++r)
                p[(size_t)r * 32] = acc[i][j][r];
        }
}

// ---------------- scan2: y2 [N*T][32] f32 -> out [N][O][T] ------------------
__launch_bounds__(64)
__global__ void scan2_k(const float* __restrict__ Y2, float* __restrict__ Out) {
    __shared__ float sb[OO * TT];
    const int n = blockIdx.x, lane = threadIdx.x;
    const float* y = Y2 + (size_t)n * TT * 32;

    float p1 = 0.f, a1 = 0.f, p2 = 0.f, a2 = 0.f;
    float buf[4];
#pragma unroll
    for (int j = 0; j < 4; ++j) buf[j] = (lane < 32) ? y[j * 32 + lane] : 0.f;

    for (int t = 0; t < TT; ++t) {
        float x = buf[t & 3];
        float xn = (t + 4 < TT && lane < 32) ? y[(t + 4) * 32 + lane] : 0.f;
        a1 = D_SR * (a1 + p1);
        p1 = D_SR * p1 + x;
        float ut = C_SR * a1;
        a2 = D_RF * (a2 + p2);
        float u = ut + C_RF * a2;
        float s = (u >= THETA) ? 1.0f : 0.0f;
        p2 = D_RF * p2 + REFS * s;
        if (lane < OO) sb[lane * TT + t] = s;
        buf[t & 3] = xn;
    }
    __syncthreads();
    float* on = Out + (size_t)n * OO * TT;
    for (int e = lane; e < OO * TT; e += 64) on[e] = sb[e];
}

extern "C" void kernel_launch(void* const* d_in, const int* in_sizes, int n_in,
                              void* d_out, int out_size, void* d_ws, size_t ws_size,
                              hipStream_t stream) {
    const float* X  = (const float*)d_in[0];
    const float* W1 = (const float*)d_in[1];
    const float* W2 = (const float*)d_in[2];
    float* out = (float*)d_out;

    const size_t s_s1b = (size_t)NN * TT * HH * 2;   // 65,536,000
    const size_t s_Xb  = (size_t)NN * TT * II * 2;   // 16,384,000
    const size_t s_W   = (size_t)HH * II * 2;        //    524,288 (x2)
    const size_t s_W2  = (size_t)32 * HH * 2;        //     65,536 (x2)
    const size_t s_y2  = (size_t)NN * TT * 32 * 4;   //  4,096,000
    const size_t s_st  = (size_t)NN * HH * 4 * 4;    //  1,048,576
    const size_t fixed = s_s1b + s_Xb + 2 * s_W + 2 * s_W2 + s_y2 + s_st;

    // choose t-chunking to fit ws: full y1 needs 131 MB, chunked 33 MB
    int chunkT, nchunk;
    if (ws_size >= (size_t)NN * TT * HH * 4 + fixed) { chunkT = TT;     nchunk = 1; }
    else                                             { chunkT = TT / 4; nchunk = 4; }
    const int Mrows = NN * chunkT;
    const int mtiles = (Mrows + 127) / 128;
    const size_t s_y1 = (size_t)mtiles * 128 * HH * 4;

    char* w = (char*)d_ws;
    float* y1  = (float*)w;              w += s_y1;
    f16*   s1b = (f16*)w;                w += s_s1b;
    f16*   Xb  = (f16*)w;                w += s_Xb;
    f16*   W1h = (f16*)w;                w += s_W;
    f16*   W1l = (f16*)w;                w += s_W;
    f16*   W2h = (f16*)w;                w += s_W2;
    f16*   W2l = (f16*)w;                w += s_W2;
    float* y2  = (float*)w;              w += s_y2;
    float* st  = (float*)w;

    prep_x<<<dim3(8, 4, NN), 256, 0, stream>>>(X, Xb);
    prep_w1<<<(HH * II) / 256, 256, 0, stream>>>(W1, W1h, W1l);
    prep_w2<<<(32 * HH) / 256, 256, 0, stream>>>(W2, W2h, W2l);

    for (int c = 0; c < nchunk; ++c) {
        gemm1_mfma<<<dim3(mtiles, HH / 128), 256, 0, stream>>>(Xb, W1h, W1l, y1, chunkT, c);
        scan1_k<<<dim3(HH / 256, NN), 256, 0, stream>>>(y1, s1b, st, chunkT, c);
    }
    gemm2_mfma<<<(NN * TT) / 128, 256, 0, stream>>>(s1b, W2h, W2l, y2);
    scan2_k<<<NN, 64, 0, stream>>>(y2, out);
}

// Round 3
// 236.298 us; speedup vs baseline: 2.0428x; 1.6480x over previous
//
#include <hip/hip_runtime.h>
#include <hip/hip_bf16.h>

// SNN forward: GEMM1(X*W1^T) -> psp+spike scan -> GEMM2(s1*W2^T) -> scan -> out
// f16 split-2 trick: W = hi + lo (both f16), residual ~2^-24 relative => MFMA
// f32-accumulate gives fp32-grade results. X and spikes are exact in f16.

#define NN 64
#define II 256
#define HH 1024
#define OO 18
#define TT 500

#define D_SR 0.9048374180359595f   // exp(-1/10)
#define C_SR 0.27182818284590454f  // e/10
#define D_RF 0.36787944117144233f  // exp(-1)
#define C_RF 2.718281828459045f    // e
#define THETA 10.0f
#define REFS (-20.0f)

typedef _Float16 f16;
typedef _Float16 f16x8 __attribute__((ext_vector_type(8)));
typedef float f32x4 __attribute__((ext_vector_type(4)));

__device__ __forceinline__ void gl2lds16(const void* g, void* l) {
    __builtin_amdgcn_global_load_lds(
        (const __attribute__((address_space(1))) void*)g,
        (__attribute__((address_space(3))) void*)l, 16, 0, 0);
}

// ---------------- prep: X [N][I][T] f32 -> Xb [N*T][I] f16 (transpose) -----
__launch_bounds__(256)
__global__ void prep_x(const float* __restrict__ X, f16* __restrict__ Xb) {
    __shared__ float tile[64][65];
    const int n = blockIdx.z, i0 = blockIdx.y * 64, t0 = blockIdx.x * 64;
    const int tx = threadIdx.x & 63, q = threadIdx.x >> 6;
    const float* Xn = X + (size_t)n * II * TT;
#pragma unroll 4
    for (int j = 0; j < 16; ++j) {
        int il = j * 4 + q;
        int t = t0 + tx;
        tile[il][tx] = (t < TT) ? Xn[(size_t)(i0 + il) * TT + t] : 0.f;
    }
    __syncthreads();
#pragma unroll 4
    for (int j = 0; j < 16; ++j) {
        int tl = j * 4 + q;
        int t = t0 + tl;
        if (t < TT)
            Xb[((size_t)n * TT + t) * II + i0 + tx] = (f16)tile[tx][tl];
    }
}

// ---------------- prep: W1 -> f16 hi/lo [H][I] ------------------------------
__launch_bounds__(256)
__global__ void prep_w1(const float* __restrict__ W1, f16* __restrict__ Wh,
                        f16* __restrict__ Wl) {
    int idx = blockIdx.x * 256 + threadIdx.x;  // < 1024*256
    float w = W1[idx];
    f16 h = (f16)w;
    f16 l = (f16)(w - (float)h);
    Wh[idx] = h;
    Wl[idx] = l;
}

// ---------------- prep: W2 -> f16 hi/lo [32 padded][H] ----------------------
__launch_bounds__(256)
__global__ void prep_w2(const float* __restrict__ W2, f16* __restrict__ Wh,
                        f16* __restrict__ Wl) {
    int idx = blockIdx.x * 256 + threadIdx.x;  // < 32*1024
    int o = idx >> 10;
    float w = (o < OO) ? W2[idx] : 0.f;
    f16 h = (f16)w;
    f16 l = (f16)(w - (float)h);
    Wh[idx] = h;
    Wl[idx] = l;
}

// ---------------- GEMM1 (MFMA, split-f16): y1_c = Xb_c * W1^T ---------------
// grid: (mtiles, 8); block 256 = 4 waves; 128x128 tile, BK=32, K=256.
__launch_bounds__(256)
__global__ void gemm1_mfma(const f16* __restrict__ Xb, const f16* __restrict__ Wh,
                           const f16* __restrict__ Wl, float* __restrict__ Y,
                           int chunkT, int c) {
    __shared__ __align__(16) f16 As[128 * 32];
    __shared__ __align__(16) f16 Bh[128 * 32];
    __shared__ __align__(16) f16 Bl[128 * 32];

    const int tid = threadIdx.x;
    const int wave = tid >> 6, lane = tid & 63;
    const int m0 = blockIdx.x * 128, h0 = blockIdx.y * 128;
    const int Mrows = NN * chunkT;

    // staging source rows (fixed across K): chunk-local r -> global Xb row
    int ra = m0 + wave * 32 + (lane >> 2);
    int ra2 = ra + 16;
    if (ra > Mrows - 1) ra = Mrows - 1;
    if (ra2 > Mrows - 1) ra2 = Mrows - 1;
    int na = ra / chunkT, na2 = ra2 / chunkT;
    const f16* gA0 = Xb + ((size_t)na * TT + (size_t)c * chunkT + (ra - na * chunkT)) * II + (lane & 3) * 8;
    const f16* gA1 = Xb + ((size_t)na2 * TT + (size_t)c * chunkT + (ra2 - na2 * chunkT)) * II + (lane & 3) * 8;
    const int rb = h0 + wave * 32 + (lane >> 2);
    const f16* gBh0 = Wh + (size_t)rb * II + (lane & 3) * 8;
    const f16* gBl0 = Wl + (size_t)rb * II + (lane & 3) * 8;

    f16* lA0 = As + (wave * 32) * 32;
    f16* lA1 = lA0 + 16 * 32;
    f16* lBh0 = Bh + (wave * 32) * 32;
    f16* lBh1 = lBh0 + 16 * 32;
    f16* lBl0 = Bl + (wave * 32) * 32;
    f16* lBl1 = lBl0 + 16 * 32;

    f32x4 acc[4][4] = {};
    const int wm = wave & 1, wn = wave >> 1;
    const int fr = lane & 15, kq = lane >> 4;

    for (int kk = 0; kk < II / 32; ++kk) {
        const int ko = kk * 32;
        gl2lds16(gA0 + ko, lA0);
        gl2lds16(gA1 + ko, lA1);
        gl2lds16(gBh0 + ko, lBh0);
        gl2lds16(gBh0 + 16 * II + ko, lBh1);
        gl2lds16(gBl0 + ko, lBl0);
        gl2lds16(gBl0 + 16 * II + ko, lBl1);
        __syncthreads();

        f16x8 a[4], bh[4], bl[4];
#pragma unroll
        for (int i = 0; i < 4; ++i) {
            a[i]  = *(const f16x8*)(As + (wm * 64 + i * 16 + fr) * 32 + kq * 8);
            bh[i] = *(const f16x8*)(Bh + (wn * 64 + i * 16 + fr) * 32 + kq * 8);
            bl[i] = *(const f16x8*)(Bl + (wn * 64 + i * 16 + fr) * 32 + kq * 8);
        }
#pragma unroll
        for (int i = 0; i < 4; ++i)
#pragma unroll
            for (int j = 0; j < 4; ++j) {
                acc[i][j] = __builtin_amdgcn_mfma_f32_16x16x32_f16(a[i], bh[j], acc[i][j], 0, 0, 0);
                acc[i][j] = __builtin_amdgcn_mfma_f32_16x16x32_f16(a[i], bl[j], acc[i][j], 0, 0, 0);
            }
        __syncthreads();
    }

    // epilogue: C col = lane&15, row = (lane>>4)*4 + reg (padded rows exist)
#pragma unroll
    for (int i = 0; i < 4; ++i)
#pragma unroll
        for (int j = 0; j < 4; ++j) {
            int rbase = m0 + wm * 64 + i * 16 + kq * 4;
            int cc = h0 + wn * 64 + j * 16 + fr;
            float* p = Y + (size_t)rbase * HH + cc;
#pragma unroll
            for (int r = 0; r < 4; ++r)
                p[(size_t)r * HH] = acc[i][j][r];
        }
}

// ---------------- scan1 (psp + spike), y1_c f32 -> s1b f16, stateful --------
// 65536 threads (1 per channel) => only 4 waves/CU. Occupancy is structural;
// achieved BW = bytes-in-flight / latency. PF=32-deep unrolled VGPR ring
// gives 8 MB in flight (vs 1 MB at PF=4, which measured 826 GB/s).
#define PF1 32
__launch_bounds__(256)
__global__ void scan1_k(const float* __restrict__ Y, f16* __restrict__ S1,
                        float* __restrict__ St, int chunkT, int c) {
    const int h = blockIdx.x * 256 + threadIdx.x;
    const int n = blockIdx.y;
    const int ch = n * HH + h;
    const float* p = Y + (size_t)n * chunkT * HH + h;
    f16* q = S1 + ((size_t)n * TT + (size_t)c * chunkT) * HH + h;

    float p1, a1, p2, a2;
    if (c == 0) {
        p1 = a1 = p2 = a2 = 0.f;
    } else {
        p1 = St[ch]; a1 = St[ch + 65536]; p2 = St[ch + 131072]; a2 = St[ch + 196608];
    }

    float buf[PF1];
#pragma unroll
    for (int j = 0; j < PF1; ++j)
        buf[j] = (j < chunkT) ? p[(size_t)j * HH] : 0.f;

    int t = 0;
    for (; t + PF1 <= chunkT; t += PF1) {
#pragma unroll
        for (int j = 0; j < PF1; ++j) {
            float x = buf[j];
            buf[j] = (t + j + PF1 < chunkT) ? p[(size_t)(t + j + PF1) * HH] : 0.f;
            a1 = D_SR * (a1 + p1);
            p1 = D_SR * p1 + x;
            float ut = C_SR * a1;
            a2 = D_RF * (a2 + p2);
            float u = ut + C_RF * a2;
            float s = (u >= THETA) ? 1.0f : 0.0f;
            p2 = D_RF * p2 + REFS * s;
            q[(size_t)(t + j) * HH] = (f16)s;
        }
    }
#pragma unroll
    for (int j = 0; j < PF1; ++j) {
        if (t + j < chunkT) {
            float x = buf[j];
            a1 = D_SR * (a1 + p1);
            p1 = D_SR * p1 + x;
            float ut = C_SR * a1;
            a2 = D_RF * (a2 + p2);
            float u = ut + C_RF * a2;
            float s = (u >= THETA) ? 1.0f : 0.0f;
            p2 = D_RF * p2 + REFS * s;
            q[(size_t)(t + j) * HH] = (f16)s;
        }
    }
    St[ch] = p1; St[ch + 65536] = a1; St[ch + 131072] = p2; St[ch + 196608] = a2;
}

// ---------------- GEMM2 (MFMA, split-f16): y2 = s1b * W2p^T -----------------
// grid: 250; block 256 = 4 waves; tile 128 rows x 32 o; K=1024, BK=32.
__launch_bounds__(256)
__global__ void gemm2_mfma(const f16* __restrict__ S1, const f16* __restrict__ W2h,
                           const f16* __restrict__ W2l, float* __restrict__ Y2) {
    __shared__ __align__(16) f16 As[128 * 32];
    __shared__ __align__(16) f16 Bh[32 * 32];
    __shared__ __align__(16) f16 Bl[32 * 32];

    const int tid = threadIdx.x;
    const int wave = tid >> 6, lane = tid & 63;
    const int m0 = blockIdx.x * 128;

    const f16* gA0 = S1 + (size_t)(m0 + wave * 32 + (lane >> 2)) * HH + (lane & 3) * 8;
    const f16* gA1 = gA0 + (size_t)16 * HH;
    const f16* gB = (wave < 2 ? W2h : W2l) + (size_t)((wave & 1) * 16 + (lane >> 2)) * HH + (lane & 3) * 8;

    f16* lA0 = As + (wave * 32) * 32;
    f16* lA1 = lA0 + 16 * 32;
    f16* lB = (wave < 2 ? Bh : Bl) + ((wave & 1) * 16) * 32;

    f32x4 acc[2][2] = {};
    const int fr = lane & 15, kq = lane >> 4;

    for (int kk = 0; kk < HH / 32; ++kk) {
        const int ko = kk * 32;
        gl2lds16(gA0 + ko, lA0);
        gl2lds16(gA1 + ko, lA1);
        gl2lds16(gB + ko, lB);
        __syncthreads();

        f16x8 a[2], bh[2], bl[2];
#pragma unroll
        for (int i = 0; i < 2; ++i) {
            a[i]  = *(const f16x8*)(As + (wave * 32 + i * 16 + fr) * 32 + kq * 8);
            bh[i] = *(const f16x8*)(Bh + (i * 16 + fr) * 32 + kq * 8);
            bl[i] = *(const f16x8*)(Bl + (i * 16 + fr) * 32 + kq * 8);
        }
#pragma unroll
        for (int i = 0; i < 2; ++i)
#pragma unroll
            for (int j = 0; j < 2; ++j) {
                acc[i][j] = __builtin_amdgcn_mfma_f32_16x16x32_f16(a[i], bh[j], acc[i][j], 0, 0, 0);
                acc[i][j] = __builtin_amdgcn_mfma_f32_16x16x32_f16(a[i], bl[j], acc[i][j], 0, 0, 0);
            }
        __syncthreads();
    }

#pragma unroll
    for (int i = 0; i < 2; ++i)
#pragma unroll
        for (int j = 0; j < 2; ++j) {
            int rbase = m0 + wave * 32 + i * 16 + kq * 4;
            int cc = j * 16 + fr;
            float* p = Y2 + (size_t)rbase * 32 + cc;
#pragma unroll
            for (int r = 0; r < 4; ++r)
                p[(size_t)r * 32] = acc[i][j][r];
        }
}

// ---------------- scan2: y2 [N*T][32] f32 -> out [N][O][T] ------------------
#define PF2 16
__launch_bounds__(64)
__global__ void scan2_k(const float* __restrict__ Y2, float* __restrict__ Out) {
    __shared__ float sb[OO * TT];
    const int n = blockIdx.x, lane = threadIdx.x;
    const float* y = Y2 + (size_t)n * TT * 32;
    const bool act = (lane < 32);

    float p1 = 0.f, a1 = 0.f, p2 = 0.f, a2 = 0.f;
    float buf[PF2];
#pragma unroll
    for (int j = 0; j < PF2; ++j) buf[j] = act ? y[j * 32 + lane] : 0.f;

    int t = 0;
    for (; t + PF2 <= TT; t += PF2) {
#pragma unroll
        for (int j = 0; j < PF2; ++j) {
            float x = buf[j];
            buf[j] = (act && t + j + PF2 < TT) ? y[(t + j + PF2) * 32 + lane] : 0.f;
            a1 = D_SR * (a1 + p1);
            p1 = D_SR * p1 + x;
            float ut = C_SR * a1;
            a2 = D_RF * (a2 + p2);
            float u = ut + C_RF * a2;
            float s = (u >= THETA) ? 1.0f : 0.0f;
            p2 = D_RF * p2 + REFS * s;
            if (lane < OO) sb[lane * TT + t + j] = s;
        }
    }
#pragma unroll
    for (int j = 0; j < PF2; ++j) {
        if (t + j < TT) {
            float x = buf[j];
            a1 = D_SR * (a1 + p1);
            p1 = D_SR * p1 + x;
            float ut = C_SR * a1;
            a2 = D_RF * (a2 + p2);
            float u = ut + C_RF * a2;
            float s = (u >= THETA) ? 1.0f : 0.0f;
            p2 = D_RF * p2 + REFS * s;
            if (lane < OO) sb[lane * TT + t + j] = s;
        }
    }
    __syncthreads();
    float* on = Out + (size_t)n * OO * TT;
    for (int e = lane; e < OO * TT; e += 64) on[e] = sb[e];
}

extern "C" void kernel_launch(void* const* d_in, const int* in_sizes, int n_in,
                              void* d_out, int out_size, void* d_ws, size_t ws_size,
                              hipStream_t stream) {
    const float* X  = (const float*)d_in[0];
    const float* W1 = (const float*)d_in[1];
    const float* W2 = (const float*)d_in[2];
    float* out = (float*)d_out;

    const size_t s_s1b = (size_t)NN * TT * HH * 2;   // 65,536,000
    const size_t s_Xb  = (size_t)NN * TT * II * 2;   // 16,384,000
    const size_t s_W   = (size_t)HH * II * 2;        //    524,288 (x2)
    const size_t s_W2  = (size_t)32 * HH * 2;        //     65,536 (x2)
    const size_t s_y2  = (size_t)NN * TT * 32 * 4;   //  4,096,000
    const size_t s_st  = (size_t)NN * HH * 4 * 4;    //  1,048,576
    const size_t fixed = s_s1b + s_Xb + 2 * s_W + 2 * s_W2 + s_y2 + s_st;

    // choose t-chunking to fit ws: full y1 needs 131 MB, chunked 33 MB
    int chunkT, nchunk;
    if (ws_size >= (size_t)NN * TT * HH * 4 + fixed) { chunkT = TT;     nchunk = 1; }
    else                                             { chunkT = TT / 4; nchunk = 4; }
    const int Mrows = NN * chunkT;
    const int mtiles = (Mrows + 127) / 128;
    const size_t s_y1 = (size_t)mtiles * 128 * HH * 4;

    char* w = (char*)d_ws;
    float* y1  = (float*)w;              w += s_y1;
    f16*   s1b = (f16*)w;                w += s_s1b;
    f16*   Xb  = (f16*)w;                w += s_Xb;
    f16*   W1h = (f16*)w;                w += s_W;
    f16*   W1l = (f16*)w;                w += s_W;
    f16*   W2h = (f16*)w;                w += s_W2;
    f16*   W2l = (f16*)w;                w += s_W2;
    float* y2  = (float*)w;              w += s_y2;
    float* st  = (float*)w;

    prep_x<<<dim3(8, 4, NN), 256, 0, stream>>>(X, Xb);
    prep_w1<<<(HH * II) / 256, 256, 0, stream>>>(W1, W1h, W1l);
    prep_w2<<<(32 * HH) / 256, 256, 0, stream>>>(W2, W2h, W2l);

    for (int c = 0; c < nchunk; ++c) {
        gemm1_mfma<<<dim3(mtiles, HH / 128), 256, 0, stream>>>(Xb, W1h, W1l, y1, chunkT, c);
        scan1_k<<<dim3(HH / 256, NN), 256, 0, stream>>>(y1, s1b, st, chunkT, c);
    }
    gemm2_mfma<<<(NN * TT) / 128, 256, 0, stream>>>(s1b, W2h, W2l, y2);
    scan2_k<<<NN, 64, 0, stream>>>(y2, out);
}

// Round 4
// 217.540 us; speedup vs baseline: 2.2190x; 1.0862x over previous
//
#include <hip/hip_runtime.h>
#include <hip/hip_bf16.h>

// SNN forward: [GEMM1(X*W1^T) + psp+spike scan FUSED] -> GEMM2(s1*W2^T) -> scan -> out
// f16 split-2 trick: W = hi + lo (both f16), residual ~2^-24 relative => MFMA
// f32-accumulate gives fp32-grade results. X and spikes are exact in f16.

#define NN 64
#define II 256
#define HH 1024
#define OO 18
#define TT 500

#define D_SR 0.9048374180359595f   // exp(-1/10)
#define C_SR 0.27182818284590454f  // e/10
#define D_RF 0.36787944117144233f  // exp(-1)
#define C_RF 2.718281828459045f    // e
#define THETA 10.0f
#define REFS (-20.0f)

typedef _Float16 f16;
typedef _Float16 f16x2 __attribute__((ext_vector_type(2)));
typedef _Float16 f16x8 __attribute__((ext_vector_type(8)));
typedef float f32x4 __attribute__((ext_vector_type(4)));

__device__ __forceinline__ void gl2lds16(const void* g, void* l) {
    __builtin_amdgcn_global_load_lds(
        (const __attribute__((address_space(1))) void*)g,
        (__attribute__((address_space(3))) void*)l, 16, 0, 0);
}

// ---------------- prep: X [N][I][T] f32 -> Xb [N*T][I] f16 (transpose) -----
__launch_bounds__(256)
__global__ void prep_x(const float* __restrict__ X, f16* __restrict__ Xb) {
    __shared__ float tile[64][65];
    const int n = blockIdx.z, i0 = blockIdx.y * 64, t0 = blockIdx.x * 64;
    const int tx = threadIdx.x & 63, q = threadIdx.x >> 6;
    const float* Xn = X + (size_t)n * II * TT;
#pragma unroll 4
    for (int j = 0; j < 16; ++j) {
        int il = j * 4 + q;
        int t = t0 + tx;
        tile[il][tx] = (t < TT) ? Xn[(size_t)(i0 + il) * TT + t] : 0.f;
    }
    __syncthreads();
#pragma unroll 4
    for (int j = 0; j < 16; ++j) {
        int tl = j * 4 + q;
        int t = t0 + tl;
        if (t < TT)
            Xb[((size_t)n * TT + t) * II + i0 + tx] = (f16)tile[tx][tl];
    }
}

// ---------------- prep: W1 -> f16 hi/lo [H][I] ------------------------------
__launch_bounds__(256)
__global__ void prep_w1(const float* __restrict__ W1, f16* __restrict__ Wh,
                        f16* __restrict__ Wl) {
    int idx = blockIdx.x * 256 + threadIdx.x;
    float w = W1[idx];
    f16 h = (f16)w;
    f16 l = (f16)(w - (float)h);
    Wh[idx] = h;
    Wl[idx] = l;
}

// ---------------- prep: W2 -> f16 hi/lo [32 padded][H] ----------------------
__launch_bounds__(256)
__global__ void prep_w2(const float* __restrict__ W2, f16* __restrict__ Wh,
                        f16* __restrict__ Wl) {
    int idx = blockIdx.x * 256 + threadIdx.x;
    int o = idx >> 10;
    float w = (o < OO) ? W2[idx] : 0.f;
    f16 h = (f16)w;
    f16 l = (f16)(w - (float)h);
    Wh[idx] = h;
    Wl[idx] = l;
}

// ---------------- FUSED layer 1: GEMM1 (split-f16 MFMA) + psp/spike scan ----
// grid (8, 64) -> 512 blocks, 256 thr. Block = (n, 128-h tile), loops 4
// t-chunks of 128. Per chunk: K-loop MFMA -> acc->LDS(y, stride 132) ->
// in-LDS sequential scan (128 thr, 8-deep ring) -> pack f16 -> global s1.
// y1 never hits HBM (-262 MB vs unfused). LDS union: 24 KB staging / 67.6 KB y.
__launch_bounds__(256)
__global__ void gemm1_scan1(const f16* __restrict__ Xb, const f16* __restrict__ Wh,
                            const f16* __restrict__ Wl, f16* __restrict__ S1) {
    __shared__ __align__(16) char smem[128 * 132 * 4];  // 67,584 B
    f16* As = (f16*)smem;                // 128x32 f16 = 8 KB
    f16* Bh = (f16*)(smem + 8192);       // 8 KB
    f16* Bl = (f16*)(smem + 16384);      // 8 KB
    float* yb = (float*)smem;            // 128 x 132 f32 (union)

    const int tid = threadIdx.x;
    const int wave = tid >> 6, lane = tid & 63;

    // XCD swizzle: all 8 h-tiles of one n land on the same XCD (f%8 fixed)
    const int f = blockIdx.y * 8 + blockIdx.x;
    const int x = f & 7, g = f >> 3;
    const int n = x * 8 + (g & 7);
    const int h0g = (g >> 3) * 128;

    const int rbl = wave * 32 + (lane >> 2);  // staged local row 0..31 per wave
    const f16* gBh0 = Wh + (size_t)(h0g + rbl) * II + (lane & 3) * 8;
    const f16* gBl0 = Wl + (size_t)(h0g + rbl) * II + (lane & 3) * 8;

    f16* lA0 = As + (wave * 32) * 32;
    f16* lA1 = lA0 + 16 * 32;
    f16* lBh0 = Bh + (wave * 32) * 32;
    f16* lBh1 = lBh0 + 16 * 32;
    f16* lBl0 = Bl + (wave * 32) * 32;
    f16* lBl1 = lBl0 + 16 * 32;

    const int wm = wave & 1, wn = wave >> 1;
    const int fr = lane & 15, kq = lane >> 4;

    float p1 = 0.f, a1 = 0.f, p2 = 0.f, a2 = 0.f;  // scan state (tid<128)

    for (int c = 0; c < 4; ++c) {
        const int t0 = c * 128;
        const int TCe = (TT - t0 < 128) ? (TT - t0) : 128;

        int r0 = rbl;      if (r0 > TCe - 1) r0 = TCe - 1;
        int r1 = rbl + 16; if (r1 > TCe - 1) r1 = TCe - 1;
        const f16* gA0 = Xb + ((size_t)n * TT + t0 + r0) * II + (lane & 3) * 8;
        const f16* gA1 = Xb + ((size_t)n * TT + t0 + r1) * II + (lane & 3) * 8;

        f32x4 acc[4][4] = {};
        for (int kk = 0; kk < II / 32; ++kk) {
            const int ko = kk * 32;
            gl2lds16(gA0 + ko, lA0);
            gl2lds16(gA1 + ko, lA1);
            gl2lds16(gBh0 + ko, lBh0);
            gl2lds16(gBh0 + 16 * II + ko, lBh1);
            gl2lds16(gBl0 + ko, lBl0);
            gl2lds16(gBl0 + 16 * II + ko, lBl1);
            __syncthreads();

            f16x8 a[4], bh[4], bl[4];
#pragma unroll
            for (int i = 0; i < 4; ++i) {
                a[i]  = *(const f16x8*)(As + (wm * 64 + i * 16 + fr) * 32 + kq * 8);
                bh[i] = *(const f16x8*)(Bh + (wn * 64 + i * 16 + fr) * 32 + kq * 8);
                bl[i] = *(const f16x8*)(Bl + (wn * 64 + i * 16 + fr) * 32 + kq * 8);
            }
#pragma unroll
            for (int i = 0; i < 4; ++i)
#pragma unroll
                for (int j = 0; j < 4; ++j) {
                    acc[i][j] = __builtin_amdgcn_mfma_f32_16x16x32_f16(a[i], bh[j], acc[i][j], 0, 0, 0);
                    acc[i][j] = __builtin_amdgcn_mfma_f32_16x16x32_f16(a[i], bl[j], acc[i][j], 0, 0, 0);
                }
            __syncthreads();
        }

        // acc -> yb (t-row major, stride 132 words: 2-way banks = free)
#pragma unroll
        for (int i = 0; i < 4; ++i)
#pragma unroll
            for (int j = 0; j < 4; ++j) {
                int tr = wm * 64 + i * 16 + kq * 4;
                int hc = wn * 64 + j * 16 + fr;
#pragma unroll
                for (int r = 0; r < 4; ++r)
                    yb[(tr + r) * 132 + hc] = acc[i][j][r];
            }
        __syncthreads();

        // sequential scan over the chunk; 8-deep LDS prefetch ring
        if (tid < 128) {
            float rb_[8];
#pragma unroll
            for (int j = 0; j < 8; ++j) rb_[j] = yb[j * 132 + tid];
            int t = 0;
            for (; t + 8 <= TCe; t += 8) {
#pragma unroll
                for (int j = 0; j < 8; ++j) {
                    float xv = rb_[j];
                    int tn = t + j + 8;
                    rb_[j] = (tn < TCe) ? yb[tn * 132 + tid] : 0.f;
                    a1 = D_SR * (a1 + p1);
                    p1 = D_SR * p1 + xv;
                    float ut = C_SR * a1;
                    a2 = D_RF * (a2 + p2);
                    float u = ut + C_RF * a2;
                    float s = (u >= THETA) ? 1.0f : 0.0f;
                    p2 = D_RF * p2 + REFS * s;
                    yb[(t + j) * 132 + tid] = s;
                }
            }
            int rem = TCe - t;
#pragma unroll
            for (int j = 0; j < 8; ++j) {
                if (j < rem) {
                    float xv = rb_[j];
                    a1 = D_SR * (a1 + p1);
                    p1 = D_SR * p1 + xv;
                    float ut = C_SR * a1;
                    a2 = D_RF * (a2 + p2);
                    float u = ut + C_RF * a2;
                    float s = (u >= THETA) ? 1.0f : 0.0f;
                    p2 = D_RF * p2 + REFS * s;
                    yb[(t + j) * 132 + tid] = s;
                }
            }
        }
        __syncthreads();

        // pack f16 and store: 4 t-rows per pass, 64 lanes x f16x2 per row
        const int rowq = tid >> 6;
#pragma unroll 4
        for (int pass = 0; pass < 32; ++pass) {
            int row = pass * 4 + rowq;
            if (row < TCe) {
                float v0 = yb[row * 132 + 2 * lane];
                float v1 = yb[row * 132 + 2 * lane + 1];
                f16x2 h2 = {(f16)v0, (f16)v1};
                *(f16x2*)(S1 + ((size_t)n * TT + t0 + row) * HH + h0g + 2 * lane) = h2;
            }
        }
        __syncthreads();
    }
}

// ---------------- GEMM2 (MFMA, split-f16): y2 = s1b * W2p^T -----------------
__launch_bounds__(256)
__global__ void gemm2_mfma(const f16* __restrict__ S1, const f16* __restrict__ W2h,
                           const f16* __restrict__ W2l, float* __restrict__ Y2) {
    __shared__ __align__(16) f16 As[128 * 32];
    __shared__ __align__(16) f16 Bh[32 * 32];
    __shared__ __align__(16) f16 Bl[32 * 32];

    const int tid = threadIdx.x;
    const int wave = tid >> 6, lane = tid & 63;
    const int m0 = blockIdx.x * 128;

    const f16* gA0 = S1 + (size_t)(m0 + wave * 32 + (lane >> 2)) * HH + (lane & 3) * 8;
    const f16* gA1 = gA0 + (size_t)16 * HH;
    const f16* gB = (wave < 2 ? W2h : W2l) + (size_t)((wave & 1) * 16 + (lane >> 2)) * HH + (lane & 3) * 8;

    f16* lA0 = As + (wave * 32) * 32;
    f16* lA1 = lA0 + 16 * 32;
    f16* lB = (wave < 2 ? Bh : Bl) + ((wave & 1) * 16) * 32;

    f32x4 acc[2][2] = {};
    const int fr = lane & 15, kq = lane >> 4;

    for (int kk = 0; kk < HH / 32; ++kk) {
        const int ko = kk * 32;
        gl2lds16(gA0 + ko, lA0);
        gl2lds16(gA1 + ko, lA1);
        gl2lds16(gB + ko, lB);
        __syncthreads();

        f16x8 a[2], bh[2], bl[2];
#pragma unroll
        for (int i = 0; i < 2; ++i) {
            a[i]  = *(const f16x8*)(As + (wave * 32 + i * 16 + fr) * 32 + kq * 8);
            bh[i] = *(const f16x8*)(Bh + (i * 16 + fr) * 32 + kq * 8);
            bl[i] = *(const f16x8*)(Bl + (i * 16 + fr) * 32 + kq * 8);
        }
#pragma unroll
        for (int i = 0; i < 2; ++i)
#pragma unroll
            for (int j = 0; j < 2; ++j) {
                acc[i][j] = __builtin_amdgcn_mfma_f32_16x16x32_f16(a[i], bh[j], acc[i][j], 0, 0, 0);
                acc[i][j] = __builtin_amdgcn_mfma_f32_16x16x32_f16(a[i], bl[j], acc[i][j], 0, 0, 0);
            }
        __syncthreads();
    }

#pragma unroll
    for (int i = 0; i < 2; ++i)
#pragma unroll
        for (int j = 0; j < 2; ++j) {
            int rbase = m0 + wave * 32 + i * 16 + kq * 4;
            int cc = j * 16 + fr;
            float* p = Y2 + (size_t)rbase * 32 + cc;
#pragma unroll
            for (int r = 0; r < 4; ++r)
                p[(size_t)r * 32] = acc[i][j][r];
        }
}

// ---------------- scan2: y2 [N*T][32] f32 -> out [N][O][T] ------------------
#define PF2 16
__launch_bounds__(64)
__global__ void scan2_k(const float* __restrict__ Y2, float* __restrict__ Out) {
    __shared__ float sb[OO * TT];
    const int n = blockIdx.x, lane = threadIdx.x;
    const float* y = Y2 + (size_t)n * TT * 32;
    const bool act = (lane < 32);

    float p1 = 0.f, a1 = 0.f, p2 = 0.f, a2 = 0.f;
    float buf[PF2];
#pragma unroll
    for (int j = 0; j < PF2; ++j) buf[j] = act ? y[j * 32 + lane] : 0.f;

    int t = 0;
    for (; t + PF2 <= TT; t += PF2) {
#pragma unroll
        for (int j = 0; j < PF2; ++j) {
            float x = buf[j];
            buf[j] = (act && t + j + PF2 < TT) ? y[(t + j + PF2) * 32 + lane] : 0.f;
            a1 = D_SR * (a1 + p1);
            p1 = D_SR * p1 + x;
            float ut = C_SR * a1;
            a2 = D_RF * (a2 + p2);
            float u = ut + C_RF * a2;
            float s = (u >= THETA) ? 1.0f : 0.0f;
            p2 = D_RF * p2 + REFS * s;
            if (lane < OO) sb[lane * TT + t + j] = s;
        }
    }
#pragma unroll
    for (int j = 0; j < PF2; ++j) {
        if (t + j < TT) {
            float x = buf[j];
            a1 = D_SR * (a1 + p1);
            p1 = D_SR * p1 + x;
            float ut = C_SR * a1;
            a2 = D_RF * (a2 + p2);
            float u = ut + C_RF * a2;
            float s = (u >= THETA) ? 1.0f : 0.0f;
            p2 = D_RF * p2 + REFS * s;
            if (lane < OO) sb[lane * TT + t + j] = s;
        }
    }
    __syncthreads();
    float* on = Out + (size_t)n * OO * TT;
    for (int e = lane; e < OO * TT; e += 64) on[e] = sb[e];
}

extern "C" void kernel_launch(void* const* d_in, const int* in_sizes, int n_in,
                              void* d_out, int out_size, void* d_ws, size_t ws_size,
                              hipStream_t stream) {
    const float* X  = (const float*)d_in[0];
    const float* W1 = (const float*)d_in[1];
    const float* W2 = (const float*)d_in[2];
    float* out = (float*)d_out;

    const size_t s_s1b = (size_t)NN * TT * HH * 2;   // 65,536,000
    const size_t s_Xb  = (size_t)NN * TT * II * 2;   // 16,384,000
    const size_t s_W   = (size_t)HH * II * 2;        //    524,288 (x2)
    const size_t s_W2  = (size_t)32 * HH * 2;        //     65,536 (x2)
    // y2: 4,096,000  => total ~87.1 MB (fits proven ws >= 133 MB)

    char* w = (char*)d_ws;
    f16*   s1b = (f16*)w;                w += s_s1b;
    f16*   Xb  = (f16*)w;                w += s_Xb;
    f16*   W1h = (f16*)w;                w += s_W;
    f16*   W1l = (f16*)w;                w += s_W;
    f16*   W2h = (f16*)w;                w += s_W2;
    f16*   W2l = (f16*)w;                w += s_W2;
    float* y2  = (float*)w;

    prep_x<<<dim3(8, 4, NN), 256, 0, stream>>>(X, Xb);
    prep_w1<<<(HH * II) / 256, 256, 0, stream>>>(W1, W1h, W1l);
    prep_w2<<<(32 * HH) / 256, 256, 0, stream>>>(W2, W2h, W2l);

    gemm1_scan1<<<dim3(8, NN), 256, 0, stream>>>(Xb, W1h, W1l, s1b);

    gemm2_mfma<<<(NN * TT) / 128, 256, 0, stream>>>(s1b, W2h, W2l, y2);
    scan2_k<<<NN, 64, 0, stream>>>(y2, out);
}